// Round 7
// baseline (482.328 us; speedup 1.0000x reference)
//
#include <hip/hip_runtime.h>
#include <math.h>

// TemporalEncoder: out[t, b, d] = (t == floor(sigmoid(x[b,d]) * (T-1))) ? 1 : 0
// B=256, D=4096, T=100. Output 419 MB fp32, only 1M cells are 1.0f (one
// spike per (b,d)) -> 99% zeros.
//
// R8: sparse strategy with OUR OWN fill-shaped zero kernel.
//   R0-R6: every data-dependent dense writer (short blocks / strided /
//     4-chunk ILP / persistent / persistent+nt / full-line nt) plateaus at
//     ~3.3 TB/s. rocclr fillBufferAligned: 6.25 TB/s, 8 VGPR, 10% occ,
//     NO LOADS. The untested configuration is a load-free constant-store
//     HIP kernel -- this round is that experiment.
//   R7: hipMemsetAsync as a graph node did NOT hit the fast fill path
//     (no fast fill dispatch appeared; poison fills degraded via overlap
//     -> 468 us). So do the zero-fill ourselves, on-stream, serialized.
//
//   zero_fill: block owns a contiguous 200 KB span; each thread streams
//     back-to-back coalesced f32x4 zero stores (1 KB/wave-instr), zero
//     loads, zero data deps. If this runs at fill BW (~67 us), sparse wins:
//     total ~= poison 268 + fill 67 + scatter ~30. If it runs at 3.3 TB/s,
//     the wall is fundamental -> revert to R0, declare roofline.
//   scatter_ones: read x (4 MB coalesced), 4 sigmoids, 4 scattered dword
//     stores of 1.0f into 4 different t-planes.

typedef __attribute__((ext_vector_type(4))) float f32x4;

__device__ __forceinline__ float sigmoidf_(float x) {
    return 1.0f / (1.0f + expf(-x));  // matches f32 expit to 0 ulp vs np ref (R1)
}

// Load-free streaming zero-fill, fill-shaped. nf = total floats.
// Each block: cpb contiguous 4-KB chunks starting at blockIdx.x * cpb.
__global__ __launch_bounds__(256) void zero_fill_kernel(
    float* __restrict__ out, long long nf, int cpb) {
    const long long total_chunks = nf >> 10;           // 4-KB chunks
    long long c0 = (long long)blockIdx.x * cpb;
    long long cend = c0 + cpb;
    if (cend > total_chunks) cend = total_chunks;
    const f32x4 z = {0.0f, 0.0f, 0.0f, 0.0f};
    float* op = out + (c0 << 10) + threadIdx.x * 4;
    // 4x unroll: 4 independent coalesced stores in flight per iteration.
    long long c = c0;
    for (; c + 4 <= cend; c += 4) {
        *reinterpret_cast<f32x4*>(op)        = z;
        *reinterpret_cast<f32x4*>(op + 1024) = z;
        *reinterpret_cast<f32x4*>(op + 2048) = z;
        *reinterpret_cast<f32x4*>(op + 3072) = z;
        op += 4096;
    }
    for (; c < cend; ++c) { *reinterpret_cast<f32x4*>(op) = z; op += 1024; }
    // tail floats (nf % 1024) handled by block 0, thread-strided
    if (blockIdx.x == 0) {
        for (long long i = (total_chunks << 10) + threadIdx.x; i < nf; i += 256)
            out[i] = 0.0f;
    }
}

__global__ __launch_bounds__(256) void scatter_ones_kernel(
    const float* __restrict__ x, float* __restrict__ out, int n, float tm1) {
    const int e = (blockIdx.x * 256 + threadIdx.x) * 4;
    if (e + 3 < n) {
        const f32x4 v = *reinterpret_cast<const f32x4*>(x + e);
        const int t0 = (int)(sigmoidf_(v.x) * tm1);
        const int t1 = (int)(sigmoidf_(v.y) * tm1);
        const int t2 = (int)(sigmoidf_(v.z) * tm1);
        const int t3 = (int)(sigmoidf_(v.w) * tm1);
        out[(size_t)t0 * n + (size_t)(e    )] = 1.0f;
        out[(size_t)t1 * n + (size_t)(e + 1)] = 1.0f;
        out[(size_t)t2 * n + (size_t)(e + 2)] = 1.0f;
        out[(size_t)t3 * n + (size_t)(e + 3)] = 1.0f;
    } else {
        for (int i = e; i < n; ++i) {
            const int t = (int)(sigmoidf_(x[i]) * tm1);
            out[(size_t)t * n + (size_t)i] = 1.0f;
        }
    }
}

extern "C" void kernel_launch(void* const* d_in, const int* in_sizes, int n_in,
                              void* d_out, int out_size, void* d_ws, size_t ws_size,
                              hipStream_t stream) {
    const float* x = (const float*)d_in[0];
    float* out = (float*)d_out;
    const int n = in_sizes[0];             // B*D = 1048576
    const float tm1 = (float)(out_size / n - 1);   // T-1 = 99

    // 1) zero the output with our fill-shaped kernel (same stream ->
    //    serialized before the scatter).
    const long long nf = (long long)out_size;            // floats
    const long long total_chunks = nf >> 10;             // 102400 for this shape
    const int fill_blocks = 2048;
    const int cpb = (int)((total_chunks + fill_blocks - 1) / fill_blocks); // 50
    zero_fill_kernel<<<fill_blocks, 256, 0, stream>>>(out, nf, cpb);

    // 2) scatter the 1M ones.
    const int n4 = (n + 3) / 4;
    const int blocks = (n4 + 255) / 256;   // 1024 for n = 2^20
    scatter_ones_kernel<<<blocks, 256, 0, stream>>>(x, out, n, tm1);
}

// Round 8
// 407.408 us; speedup vs baseline: 1.1839x; 1.1839x over previous
//
#include <hip/hip_runtime.h>
#include <math.h>

// TemporalEncoder: out[t, b, d] = (t == floor(sigmoid(x[b,d]) * (T-1))) ? 1 : 0
// B=256, D=4096, T=100. Output 419 MB fp32 -> pure write-BW bound.
//
// R9 theory (fits all 8 prior experiments): the ~3.3 TB/s wall shared by
// every writer so far (R0 short blocks, R3 strided, R4 4-chunk, R5
// persistent, R6 nt, R8 LOAD-FREE zero-fill) is WRITE-STREAM CONCURRENCY.
// All of them ran at ~77% occupancy: thousands of waves each owning a
// different region -> thousands of interleaved HBM write streams -> DRAM
// row-buffer thrash. rocclr fillBufferAligned runs at 10% OCCUPANCY
// (~200-256 blocks, grid-stride) and 6.25 TB/s: the whole device writes
// one narrow moving address window.
//
// R9: grid = n>>12 = 256 blocks (1/CU), grid-stride over 4-KB chunks.
// At step k the device writes the contiguous window [k MB, (k+1) MB).
// With G = cpp/4 blocks (cpp = chunks/plane), block b only ever touches
// plane-local chunks {b, b+G, b+2G, b+3G} -> preload those 4 st words into
// registers ONCE; the loop body is load-free: compare+select+store.
// t = k>>2 exactly (b < G guarantees no carry).
//
// Kept lessons: regular write-back stores only (R2: nt+partial lines =
// 2.2x WRITE_SIZE; R6: nt+full lines = no gain); stores lane-coalesced
// 1 KB/instruction (R3).

typedef __attribute__((ext_vector_type(4))) float f32x4;

__device__ __forceinline__ float sigmoidf_(float x) {
    return 1.0f / (1.0f + expf(-x));  // matches f32 expit to 0 ulp vs np ref (R1)
}

__device__ __forceinline__ f32x4 onehot4_(unsigned int sw, unsigned int tu) {
    f32x4 o;
    o.x = (((sw      ) & 0xffu) == tu) ? 1.0f : 0.0f;
    o.y = (((sw >>  8) & 0xffu) == tu) ? 1.0f : 0.0f;
    o.z = (((sw >> 16) & 0xffu) == tu) ? 1.0f : 0.0f;
    o.w = (((sw >> 24)        ) == tu) ? 1.0f : 0.0f;
    return o;
}

__global__ __launch_bounds__(256) void spike_time_kernel(
    const float* __restrict__ x, unsigned char* __restrict__ st,
    int n, float tm1) {
    const int e = (blockIdx.x * 256 + threadIdx.x) * 4;
    if (e + 3 < n) {
        f32x4 v = *reinterpret_cast<const f32x4*>(x + e);
        uchar4 s;
        s.x = (unsigned char)(int)(sigmoidf_(v.x) * tm1);
        s.y = (unsigned char)(int)(sigmoidf_(v.y) * tm1);
        s.z = (unsigned char)(int)(sigmoidf_(v.z) * tm1);
        s.w = (unsigned char)(int)(sigmoidf_(v.w) * tm1);
        *reinterpret_cast<uchar4*>(st + e) = s;
    } else {
        for (int i = e; i < n; ++i)
            st[i] = (unsigned char)(int)(sigmoidf_(x[i]) * tm1);
    }
}

// Pass 2: fill-shaped grid-stride writer.
// Preconditions (checked on host): n % 4096 == 0, G = n>>12 = cpp/4,
// grid = G blocks of 256 threads. nk = 4*T steps; t = k>>2.
__global__ __launch_bounds__(256) void write_onehot_gs_kernel(
    const unsigned char* __restrict__ st, float* __restrict__ out,
    int G, int nk) {
    const int b = blockIdx.x;
    const int lane4 = threadIdx.x * 4;
    // Preload the only 4 st words this block ever needs (L2/L1 hit).
    const unsigned int s0 = *reinterpret_cast<const unsigned int*>(
        st + ((size_t)b << 10) + lane4);
    const unsigned int s1 = *reinterpret_cast<const unsigned int*>(
        st + ((size_t)(b + G) << 10) + lane4);
    const unsigned int s2 = *reinterpret_cast<const unsigned int*>(
        st + ((size_t)(b + 2 * G) << 10) + lane4);
    const unsigned int s3 = *reinterpret_cast<const unsigned int*>(
        st + ((size_t)(b + 3 * G) << 10) + lane4);

    const size_t step = (size_t)G << 10;          // floats between steps
    float* op = out + ((size_t)b << 10) + lane4;
    // nk % 4 == 0 always (nk = 4*T). Unrolled by 4: one t-plane per group,
    // tu uniform across the group; loop body has zero memory loads.
    for (int k = 0; k < nk; k += 4) {
        const unsigned int tu = (unsigned int)(k >> 2);
        *reinterpret_cast<f32x4*>(op)            = onehot4_(s0, tu);
        *reinterpret_cast<f32x4*>(op + step)     = onehot4_(s1, tu);
        *reinterpret_cast<f32x4*>(op + 2 * step) = onehot4_(s2, tu);
        *reinterpret_cast<f32x4*>(op + 3 * step) = onehot4_(s3, tu);
        op += 4 * step;
    }
}

// Fallback for shapes the fast path doesn't cover.
__global__ __launch_bounds__(256) void fused_onehot_kernel(
    const float* __restrict__ x, float* __restrict__ out, int n, float tm1) {
    const int t = blockIdx.y;
    const int e = (blockIdx.x * 256 + threadIdx.x) * 4;
    if (e + 3 < n) {
        f32x4 v = *reinterpret_cast<const f32x4*>(x + e);
        f32x4 o;
        o.x = ((int)(sigmoidf_(v.x) * tm1) == t) ? 1.0f : 0.0f;
        o.y = ((int)(sigmoidf_(v.y) * tm1) == t) ? 1.0f : 0.0f;
        o.z = ((int)(sigmoidf_(v.z) * tm1) == t) ? 1.0f : 0.0f;
        o.w = ((int)(sigmoidf_(v.w) * tm1) == t) ? 1.0f : 0.0f;
        *reinterpret_cast<f32x4*>(out + (size_t)t * n + e) = o;
    } else {
        for (int i = e; i < n; ++i)
            out[(size_t)t * n + i] = ((int)(sigmoidf_(x[i]) * tm1) == t) ? 1.0f : 0.0f;
    }
}

extern "C" void kernel_launch(void* const* d_in, const int* in_sizes, int n_in,
                              void* d_out, int out_size, void* d_ws, size_t ws_size,
                              hipStream_t stream) {
    const float* x = (const float*)d_in[0];
    float* out = (float*)d_out;
    const int n = in_sizes[0];        // B*D = 1048576
    const int T = out_size / n;       // 100
    const float tm1 = (float)(T - 1);

    const int n4 = (n + 3) / 4;
    const int blocks4 = (n4 + 255) / 256;     // pass-1 / fused grid

    if (ws_size >= (size_t)n && T <= 256 && (n & 4095) == 0) {
        unsigned char* st = (unsigned char*)d_ws;
        spike_time_kernel<<<blocks4, 256, 0, stream>>>(x, st, n, tm1);
        const int G = n >> 12;        // 256 blocks for n = 2^20 (1 per CU)
        const int nk = 4 * T;         // 400 steps, t = k>>2
        write_onehot_gs_kernel<<<G, 256, 0, stream>>>(st, out, G, nk);
    } else {
        dim3 grid(blocks4, T);
        fused_onehot_kernel<<<grid, 256, 0, stream>>>(x, out, n, tm1);
    }
}